// Round 7
// baseline (615.001 us; speedup 1.0000x reference)
//
#include <hip/hip_runtime.h>
#include <hip/hip_bf16.h>

typedef unsigned short u16;
typedef u16  u16x4 __attribute__((ext_vector_type(4)));
typedef u16  u16x8 __attribute__((ext_vector_type(8)));
typedef __bf16 bf16;
typedef bf16 bf16x8 __attribute__((ext_vector_type(8)));
typedef float f32x4 __attribute__((ext_vector_type(4)));

__device__ __forceinline__ float b2f(u16 u){ return __uint_as_float(((unsigned)u)<<16); }
__device__ __forceinline__ u16 f2b(float f){ bf16 h = (bf16)f; return __builtin_bit_cast(u16, h); }
__device__ __forceinline__ float lrelu(float v){ return v > 0.f ? v : 0.2f*v; }

// async global->LDS, 16B per lane; lds base must be wave-uniform (HW adds lane*16)
__device__ __forceinline__ void gll16(const u16* g, u16* l){
  __builtin_amdgcn_global_load_lds(
    (const __attribute__((address_space(1))) unsigned int*)(const void*)g,
    (__attribute__((address_space(3))) unsigned int*)(void*)l, 16, 0, 0);
}
#define VMCNTW(n) asm volatile("s_waitcnt vmcnt(" #n ")" ::: "memory")
#define BAR()    { asm volatile("" ::: "memory"); __builtin_amdgcn_s_barrier(); asm volatile("" ::: "memory"); }

// ---------------- prep kernels ----------------

__global__ __launch_bounds__(256) void prep_w_up(const float* __restrict__ up_w,
                                                 u16* __restrict__ Wup_t, float* __restrict__ wsq_up){
  const int t = blockIdx.x*256 + threadIdx.x;          // 512*512
  const int i = t & 511, o = t >> 9;
  const float* src = up_w + ((i<<9) + o)*9;
  float sq = 0.f;
  #pragma unroll
  for (int ky=0; ky<3; ++ky)
    #pragma unroll
    for (int kx=0; kx<3; ++kx){
      float w = src[ky*3+kx];
      sq += w*w;
      Wup_t[ (((2-ky)*3 + (2-kx))<<18) + (o<<9) + i ] = f2b(w);
    }
  wsq_up[(o<<9)+i] = sq;
}

__global__ __launch_bounds__(256) void prep_w_c(const float* __restrict__ c_w,
                                                u16* __restrict__ Wc_t, float* __restrict__ wsq_c){
  const int t = blockIdx.x*256 + threadIdx.x;
  const int i = t & 511, o = t >> 9;
  const float* src = c_w + ((o<<9) + i)*9;
  float sq = 0.f;
  #pragma unroll
  for (int tap=0; tap<9; ++tap){
    float w = src[tap];
    sq += w*w;
    Wc_t[ (tap<<18) + (o<<9) + i ] = f2b(w);
  }
  wsq_c[(o<<9)+i] = sq;
}

__global__ __launch_bounds__(256) void prep_s(const float* __restrict__ v,
    const float* __restrict__ up_sw, const float* __restrict__ up_sb,
    const float* __restrict__ c_sw,  const float* __restrict__ c_sb,
    const float* __restrict__ rgb_sw,const float* __restrict__ rgb_sb,
    float* __restrict__ s_up, float* __restrict__ s_c, float* __restrict__ s_rgb){
  const int t = blockIdx.x*256 + threadIdx.x;          // 8*512
  const int j = t & 511, n = t >> 9;
  const float* vn = v + (n<<9);
  float a=0.f, b=0.f, c=0.f;
  for (int l=0; l<512; ++l){
    float vl = vn[l];
    a += vl*up_sw[(l<<9)+j];
    b += vl*c_sw[(l<<9)+j];
    c += vl*rgb_sw[(l<<9)+j];
  }
  s_up[t] = a + up_sb[j];
  s_c[t]  = b + c_sb[j];
  s_rgb[t]= c + rgb_sb[j];
}

__global__ __launch_bounds__(256) void prep_sigma(const float* __restrict__ wsq_up, const float* __restrict__ wsq_c,
    const float* __restrict__ s_up, const float* __restrict__ s_c,
    float* __restrict__ sinv_up, float* __restrict__ sinv_c){
  const int t = blockIdx.x*256 + threadIdx.x;          // 8*512
  const int o = t & 511, n = t >> 9;
  const float* su = s_up + (n<<9);
  const float* sc = s_c  + (n<<9);
  const float* wu = wsq_up + (o<<9);
  const float* wc = wsq_c  + (o<<9);
  float au=0.f, ac=0.f;
  for (int l=0; l<512; ++l){
    float s1 = su[l]; au += wu[l]*s1*s1;
    float s2 = sc[l]; ac += wc[l]*s2*s2;
  }
  sinv_up[t] = 1.f/sqrtf(au + 1e-8f);
  sinv_c[t]  = 1.f/sqrtf(ac + 1e-8f);
}

// zero only the padding ring of h1s [8][66][66][512] (interior written by up_conv)
__global__ __launch_bounds__(256) void zero_h1s_ring(u16* __restrict__ h1s){
  const int t = blockIdx.x*256 + threadIdx.x;   // 520*256
  const int chunk = t & 63;
  const int cg = t >> 6;                         // 0..2079
  const int n = cg / 260, c = cg - n*260;
  int Y, X;
  if (c < 66){ Y = 0; X = c; }
  else if (c < 132){ Y = 65; X = c - 66; }
  else if (c < 196){ Y = c - 131; X = 0; }
  else { Y = c - 195; X = 65; }
  u16x8 z = {0,0,0,0,0,0,0,0};
  *(u16x8*)&h1s[ (size_t)(((n*66 + Y)*66 + X)<<9) + (chunk<<3) ] = z;
}

// zero only the padding ring of xp [8][33][36][512] (interior p<32,q<32 written by fill_xp)
__global__ __launch_bounds__(256) void zero_xp_ring(u16* __restrict__ xp){
  const int t = blockIdx.x*256 + threadIdx.x;   // 328*256
  const int chunk = t & 63;
  const int cg = t >> 6;                         // 0..1311
  const int n = cg / 164, c = cg - n*164;
  int p, q;
  if (c < 128){ p = c >> 2; q = 32 + (c & 3); }
  else { p = 32; q = c - 128; }
  u16x8 z = {0,0,0,0,0,0,0,0};
  *(u16x8*)&xp[ (size_t)(((n*33 + p)*36 + q)<<9) + (chunk<<3) ] = z;
}

// x [8,512,32,32] f32 -> xp NHWC bf16 [n][33][36][512], value = x * s_up[n][ch]
__global__ __launch_bounds__(256) void fill_xp(const float* __restrict__ x,
    const float* __restrict__ s_up, u16* __restrict__ xp){
  const int b = blockIdx.x;            // 256
  const int n = b>>5, p = b&31;
  const int t = threadIdx.x;
  const int q = t&31, g = t>>5;        // g 0..7
  const int cb = g<<6;
  #pragma unroll
  for (int j=0;j<8;++j){
    const int ch0 = cb + (j<<3);
    u16x8 pk;
    #pragma unroll
    for (int e=0;e<8;++e){
      float vv = x[ (((n<<9)+ch0+e)<<10) + (p<<5) + q ] * s_up[(n<<9)+ch0+e];
      pk[e] = f2b(vv);
    }
    *(u16x8*)&xp[ (((n*33+p)*36 + q)<<9) + ch0 ] = pk;
  }
}

// ---------------- up-conv (modulated conv_transpose 2x) ----------------
// uniform phase pipeline: A->LDS 3-buf (gll16), B->regs dbuf, 1 barrier/phase
__global__ __launch_bounds__(256, 2) void up_conv_k(
    const u16* __restrict__ xp, const u16* __restrict__ Wup_t,
    const float* __restrict__ sinv_up, const float* __restrict__ up_b,
    const float* __restrict__ s_c, const float* __restrict__ noise1,
    const float* __restrict__ nstr, u16* __restrict__ h1s)
{
  __shared__ __align__(16) u16 Aa[24576];       // 3 x [128][64]
  const int braw = blockIdx.x;
  const int bid = ((braw&7)<<7) | (braw>>3);    // XCD swizzle: n pinned per XCD
  const int og = bid & 3, tile = (bid>>2)&7, cls = (bid>>5)&3, n = bid>>7;
  const int cy = cls>>1, cx = cls&1;
  const int o0 = og<<7, r0 = tile<<2;
  const int tid = threadIdx.x;
  const int lane = tid & 63, wave = tid>>6;
  const int l15 = lane & 15, l4 = lane>>4;
  const int wm = wave>>1, wn = wave&1;
  const int wub = tid & ~63;
  const int nt = (cy?2:1)*(cx?2:1);
  const int lg = (nt==4)?2:((nt==2)?1:0);
  const int NPH = nt<<3;

  f32x4 acc[4][4];
  #pragma unroll
  for (int i2=0;i2<4;++i2)
    #pragma unroll
    for (int j2=0;j2<4;++j2){ f32x4 z = {0.f,0.f,0.f,0.f}; acc[i2][j2]=z; }

  auto parms = [&](int p, int& tap, int& dp, int& dq, int& i0n){
    const int ci_ = p >> lg, t = p & (nt-1);
    const int ti = cx ? (t>>1) : t;
    const int tj = cx ? (t&1) : 0;
    const int a = cy ? (ti<<1) : 1;
    const int b = cx ? (tj<<1) : 1;
    tap = a*3 + b;
    dp = (cy + a - 1) >> 1;
    dq = (cx + b - 1) >> 1;
    i0n = ci_ << 6;
  };
  auto issueA = [&](int pn){
    int tap, dp, dq, i0n; parms(pn, tap, dp, dq, i0n);
    const int bo = (pn % 3) << 13;
    #pragma unroll
    for (int k=0;k<4;++k){
      const int q = (k<<8) + tid;
      const int o = q>>3, pc = q&7;
      const int cl = pc ^ (o&7);
      gll16(Wup_t + (tap<<18) + ((o0+o)<<9) + i0n + (cl<<3),
            Aa + bo + (((k<<8)+wub)<<3));
    }
  };
  auto issueB = [&](int pn, u16x8 (&bn)[8]){
    int tap, dp, dq, i0n; parms(pn, tap, dp, dq, i0n);
    #pragma unroll
    for (int fn=0; fn<4; ++fn){
      const int rr = (wn<<1) + (fn>>1), c = ((fn&1)<<4) + l15;
      const size_t cb = ((size_t)((n*33 + r0+rr+dp)*36 + (c+dq)) << 9) + i0n;
      bn[fn*2+0] = *(const u16x8*)(xp + cb + (l4<<3));
      bn[fn*2+1] = *(const u16x8*)(xp + cb + ((4+l4)<<3));
    }
  };
  auto compute = [&](int p, u16x8 (&bc)[8]){
    const u16* Ab = Aa + ((p % 3) << 13);
    bf16x8 af[4][2];
    #pragma unroll
    for (int fm=0;fm<4;++fm){
      const int o_r = (wm<<6)+(fm<<4)+l15;
      #pragma unroll
      for (int kh=0;kh<2;++kh)
        af[fm][kh] = *(const bf16x8*)&Ab[ ((o_r<<3) + (((kh<<2)+l4) ^ (l15&7)))<<3 ];
    }
    __builtin_amdgcn_s_setprio(1);
    #pragma unroll
    for (int kh=0;kh<2;++kh)
      #pragma unroll
      for (int fm=0;fm<4;++fm)
        #pragma unroll
        for (int fn=0;fn<4;++fn)
          acc[fm][fn] = __builtin_amdgcn_mfma_f32_16x16x32_bf16(
              af[fm][kh], __builtin_bit_cast(bf16x8, bc[fn*2+kh]), acc[fm][fn], 0,0,0);
    __builtin_amdgcn_s_setprio(0);
  };

  u16x8 bA[8], bB[8];
  issueA(0); issueB(0, bA);
  #pragma unroll 1
  for (int pp=0; pp<NPH; pp+=2){
    issueA(pp+1); issueB(pp+1, bB);
    VMCNTW(12);
    BAR();
    compute(pp, bA);
    if (pp+2 < NPH){ issueA(pp+2); issueB(pp+2, bA); VMCNTW(12); }
    else { VMCNTW(0); }
    BAR();
    compute(pp+1, bB);
  }

  // epilogue: demod + bias + noise + lrelu, fold s_c, store NHWC u16x4
  const float ns = nstr[0];
  #pragma unroll
  for (int fm=0; fm<4; ++fm){
    const int oo0 = o0 + (wm<<6) + (fm<<4) + (l4<<2);
    float si[4], bb[4], sc2[4];
    #pragma unroll
    for (int r=0;r<4;++r){
      si[r] = sinv_up[(n<<9)+oo0+r];
      bb[r] = up_b[oo0+r];
      sc2[r]= s_c[(n<<9)+oo0+r];
    }
    #pragma unroll
    for (int fn=0; fn<4; ++fn){
      const int rr = (wn<<1) + (fn>>1), c = ((fn&1)<<4) + l15;
      const int Y = ((r0+rr)<<1) + cy, X = (c<<1) + cx;
      const float nz = ns * noise1[(n<<12) + (Y<<6) + X];
      u16x4 pk;
      #pragma unroll
      for (int r=0;r<4;++r){
        float v2 = acc[fm][fn][r]*si[r] + bb[r] + nz;
        pk[r] = f2b(lrelu(v2) * sc2[r]);
      }
      *(u16x4*)&h1s[ (size_t)(((n*66 + Y+1)*66 + (X+1))<<9) + oo0 ] = pk;
    }
  }
}

// ---------------- 3x3 modulated conv ----------------
// 72 uniform phases (ci x tap), A->LDS 3-buf, B->regs dbuf, 1 barrier/phase
__global__ __launch_bounds__(256, 2) void conv3x3_k(
    const u16* __restrict__ h1s, const u16* __restrict__ Wc_t,
    const float* __restrict__ sinv_c, const float* __restrict__ c_b,
    const float* __restrict__ noise2, const float* __restrict__ nstr,
    float* __restrict__ outh)
{
  __shared__ __align__(16) u16 Aa[24576];       // 3 x [128][64]
  const int braw = blockIdx.x;
  const int bid = ((braw&7)<<7) | (braw>>3);    // XCD swizzle
  const int og = bid & 3, yp = (bid>>2)&31, n = bid>>7;
  const int o0 = og<<7, y0 = yp<<1;
  const int tid = threadIdx.x;
  const int lane = tid & 63, wave = tid>>6;
  const int l15 = lane & 15, l4 = lane>>4;
  const int wm = wave>>1, wn = wave&1;
  const int wub = tid & ~63;

  f32x4 acc[4][4];
  #pragma unroll
  for (int i2=0;i2<4;++i2)
    #pragma unroll
    for (int j2=0;j2<4;++j2){ f32x4 z = {0.f,0.f,0.f,0.f}; acc[i2][j2]=z; }

  auto issueA = [&](int pn){
    const int cin = (int)((unsigned)pn / 9u);
    const int tapn = pn - cin*9;
    const int i0n = cin << 6;
    const int bo = (pn % 3) << 13;
    #pragma unroll
    for (int k=0;k<4;++k){
      const int q = (k<<8) + tid;
      const int o = q>>3, pc = q&7;
      const int cl = pc ^ (o&7);
      gll16(Wc_t + (tapn<<18) + ((o0+o)<<9) + i0n + (cl<<3),
            Aa + bo + (((k<<8)+wub)<<3));
    }
  };
  auto issueB = [&](int pn, u16x8 (&bn)[8]){
    const int cin = (int)((unsigned)pn / 9u);
    const int tapn = pn - cin*9;
    const int kyn = tapn/3, kxn = tapn - kyn*3;
    const int i0n = cin << 6;
    #pragma unroll
    for (int fn=0; fn<4; ++fn){
      const int colx = (fn<<4) + l15 + kxn;
      const size_t cb = ((size_t)((n*66 + y0+wn+kyn)*66 + colx) << 9) + i0n;
      bn[fn*2+0] = *(const u16x8*)(h1s + cb + (l4<<3));
      bn[fn*2+1] = *(const u16x8*)(h1s + cb + ((4+l4)<<3));
    }
  };
  auto compute = [&](int p, u16x8 (&bc)[8]){
    const u16* Ab = Aa + ((p % 3) << 13);
    bf16x8 af[4][2];
    #pragma unroll
    for (int fm=0;fm<4;++fm){
      const int o_r = (wm<<6)+(fm<<4)+l15;
      #pragma unroll
      for (int kh=0;kh<2;++kh)
        af[fm][kh] = *(const bf16x8*)&Ab[ ((o_r<<3) + (((kh<<2)+l4) ^ (l15&7)))<<3 ];
    }
    __builtin_amdgcn_s_setprio(1);
    #pragma unroll
    for (int kh=0;kh<2;++kh)
      #pragma unroll
      for (int fm=0;fm<4;++fm)
        #pragma unroll
        for (int fn=0;fn<4;++fn)
          acc[fm][fn] = __builtin_amdgcn_mfma_f32_16x16x32_bf16(
              af[fm][kh], __builtin_bit_cast(bf16x8, bc[fn*2+kh]), acc[fm][fn], 0,0,0);
    __builtin_amdgcn_s_setprio(0);
  };

  u16x8 bA[8], bB[8];
  issueA(0); issueB(0, bA);
  #pragma unroll 1
  for (int pp=0; pp<72; pp+=2){
    issueA(pp+1); issueB(pp+1, bB);
    VMCNTW(12);
    BAR();
    compute(pp, bA);
    if (pp+2 < 72){ issueA(pp+2); issueB(pp+2, bA); VMCNTW(12); }
    else { VMCNTW(0); }
    BAR();
    compute(pp+1, bB);
  }

  const float ns = nstr[0];
  #pragma unroll
  for (int fm=0; fm<4; ++fm){
    #pragma unroll
    for (int r=0;r<4;++r){
      const int oo = o0 + (wm<<6)+(fm<<4)+(l4<<2)+r;
      const float si = sinv_c[(n<<9)+oo], bb = c_b[oo];
      #pragma unroll
      for (int fn=0; fn<4; ++fn){
        const int xq = (fn<<4)+l15;
        const int Y = y0 + wn;
        float v2 = acc[fm][fn][r]*si + bb + ns*noise2[(n<<12)+(Y<<6)+xq];
        outh[ (size_t)(((n<<9)+oo)<<12) + (Y<<6) + xq ] = lrelu(v2);
      }
    }
  }
}

// ---------------- toRGB + bilinear skip ----------------
__global__ __launch_bounds__(256) void rgb_k(const float* __restrict__ h2,
    const float* __restrict__ s_rgb, const float* __restrict__ rgb_w, const float* __restrict__ rgb_b,
    const float* __restrict__ yin, float* __restrict__ out1)
{
  __shared__ float coef[3][512];
  __shared__ float part[4][3][64];
  const int braw = blockIdx.x;
  const int sb = ((braw&7)<<6) | (braw>>3);    // XCD swizzle (512 blocks)
  const int n = sb>>6, Y = sb&63;
  const int tid = threadIdx.x;
  for (int t = tid; t < 1536; t += 256){
    int c = t>>9, o = t&511;
    coef[c][o] = rgb_w[(c<<9)+o]*s_rgb[(n<<9)+o];
  }
  __syncthreads();
  const int wave = tid>>6, lane = tid&63;
  const float* base = h2 + ((size_t)(n<<9))*4096 + (Y<<6) + lane;
  float a0=0.f,a1=0.f,a2=0.f;
  for (int e=0;e<128;++e){
    int o = (wave<<7)+e;
    float h = base[(size_t)o<<12];
    a0 += h*coef[0][o]; a1 += h*coef[1][o]; a2 += h*coef[2][o];
  }
  part[wave][0][lane]=a0; part[wave][1][lane]=a1; part[wave][2][lane]=a2;
  __syncthreads();
  if (tid < 192){
    const int c = tid>>6, x2 = tid&63;
    float s = part[0][c][x2]+part[1][c][x2]+part[2][c][x2]+part[3][c][x2] + rgb_b[c];
    s = lrelu(s);
    float fy = 0.5f*Y - 0.25f, fx = 0.5f*x2 - 0.25f;
    int y0i = (int)floorf(fy); float wy = fy - y0i;
    int x0i = (int)floorf(fx); float wx = fx - x0i;
    int y0c = y0i<0?0:y0i, y1c = y0i+1>31?31:y0i+1;
    int x0c = x0i<0?0:x0i, x1c = x0i+1>31?31:x0i+1;
    const float* yb = yin + ((n*3 + c)<<10);
    float v00 = yb[(y0c<<5)+x0c], v01 = yb[(y0c<<5)+x1c];
    float v10 = yb[(y1c<<5)+x0c], v11 = yb[(y1c<<5)+x1c];
    float yup = (1.f-wy)*((1.f-wx)*v00 + wx*v01) + wy*((1.f-wx)*v10 + wx*v11);
    out1[ (((n*3+c)<<12)) + (Y<<6) + x2 ] = yup + s;
  }
}

// ---------------- launch ----------------
extern "C" void kernel_launch(void* const* d_in, const int* in_sizes, int n_in,
                              void* d_out, int out_size, void* d_ws, size_t ws_size,
                              hipStream_t stream) {
  const float* x      = (const float*)d_in[0];
  const float* v      = (const float*)d_in[1];
  const float* yin    = (const float*)d_in[2];
  const float* noise1 = (const float*)d_in[3];
  const float* noise2 = (const float*)d_in[4];
  const float* up_w   = (const float*)d_in[5];
  const float* up_b   = (const float*)d_in[6];
  const float* up_sw  = (const float*)d_in[7];
  const float* up_sb  = (const float*)d_in[8];
  const float* c_w    = (const float*)d_in[9];
  const float* c_b    = (const float*)d_in[10];
  const float* c_sw   = (const float*)d_in[11];
  const float* c_sb   = (const float*)d_in[12];
  const float* rgb_w  = (const float*)d_in[13];
  const float* rgb_b  = (const float*)d_in[14];
  const float* rgb_sw = (const float*)d_in[15];
  const float* rgb_sb = (const float*)d_in[16];
  const float* nstr   = (const float*)d_in[17];

  char* w = (char*)d_ws;
  u16*   Wup_t  = (u16*)(w);                  //  4,718,592 B
  u16*   Wc_t   = (u16*)(w + 4718592);        //  4,718,592 B
  float* wsq_up = (float*)(w + 9437184);      //  1,048,576 B
  float* wsq_c  = (float*)(w + 10485760);     //  1,048,576 B
  float* s_up   = (float*)(w + 11534336);
  float* s_c    = (float*)(w + 11550720);
  float* s_rgb  = (float*)(w + 11567104);
  float* sinv_up= (float*)(w + 11583488);
  float* sinv_c = (float*)(w + 11599872);
  u16*   xp     = (u16*)(w + 11616256);       //  9,732,096 B  NHWC [8][33][36][512]
  u16*   h1s    = (u16*)(w + 21348352);       // 35,684,352 B  NHWC [8][66][66][512]

  float* outh = (float*)d_out;                 // [8,512,64,64]
  float* out1 = (float*)d_out + 16777216;      // [8,3,64,64]

  prep_w_up    <<<1024, 256, 0, stream>>>(up_w, Wup_t, wsq_up);
  prep_w_c     <<<1024, 256, 0, stream>>>(c_w,  Wc_t,  wsq_c);
  prep_s       <<<16,   256, 0, stream>>>(v, up_sw, up_sb, c_sw, c_sb, rgb_sw, rgb_sb, s_up, s_c, s_rgb);
  prep_sigma   <<<16,   256, 0, stream>>>(wsq_up, wsq_c, s_up, s_c, sinv_up, sinv_c);
  zero_xp_ring <<<328,  256, 0, stream>>>(xp);
  zero_h1s_ring<<<520,  256, 0, stream>>>(h1s);
  fill_xp      <<<256,  256, 0, stream>>>(x, s_up, xp);
  up_conv_k    <<<1024, 256, 0, stream>>>(xp, Wup_t, sinv_up, up_b, s_c, noise1, nstr, h1s);
  conv3x3_k    <<<1024, 256, 0, stream>>>(h1s, Wc_t, sinv_c, c_b, noise2, nstr, outh);
  rgb_k        <<<512,  256, 0, stream>>>(outh, s_rgb, rgb_w, rgb_b, yin, out1);
}

// Round 8
// 431.819 us; speedup vs baseline: 1.4242x; 1.4242x over previous
//
#include <hip/hip_runtime.h>
#include <hip/hip_bf16.h>

typedef unsigned short u16;
typedef u16  u16x4 __attribute__((ext_vector_type(4)));
typedef u16  u16x8 __attribute__((ext_vector_type(8)));
typedef __bf16 bf16;
typedef bf16 bf16x8 __attribute__((ext_vector_type(8)));
typedef float f32x4 __attribute__((ext_vector_type(4)));

__device__ __forceinline__ u16 f2b(float f){ bf16 h = (bf16)f; return __builtin_bit_cast(u16, h); }
__device__ __forceinline__ float lrelu(float v){ return v > 0.f ? v : 0.2f*v; }

// async global->LDS, 16B per lane; lds base wave-uniform (HW adds lane*16)
__device__ __forceinline__ void gll16(const u16* g, u16* l){
  __builtin_amdgcn_global_load_lds(
    (const __attribute__((address_space(1))) unsigned int*)(const void*)g,
    (__attribute__((address_space(3))) unsigned int*)(void*)l, 16, 0, 0);
}
#define VMCNT0() asm volatile("s_waitcnt vmcnt(0)" ::: "memory")
#define BAR()    { asm volatile("" ::: "memory"); __builtin_amdgcn_s_barrier(); asm volatile("" ::: "memory"); }

// ---------------- prep kernels ----------------

// up_w [i512][o512][3][3] -> Wup3: per-cls layout (flipped taps grouped per phase-group)
// cls = cy*2+cx from flipped (a,b); tile (cls,g,og,ci) = [o128][idx(NT)][ch32] contiguous
__global__ __launch_bounds__(256) void prep_w_up(const float* __restrict__ up_w,
                                                 u16* __restrict__ Wup3, float* __restrict__ wsq_up){
  const int t = blockIdx.x*256 + threadIdx.x;          // 512*512
  const int i = t & 511, o = t >> 9;
  const float* src = up_w + ((i<<9) + o)*9;
  const int og = o>>7, o7 = o&127, ci = i>>5, ch = i&31;
  const int clsBase[4] = {0, 262144, 786432, 1310720};
  float sq = 0.f;
  #pragma unroll
  for (int ky=0; ky<3; ++ky)
    #pragma unroll
    for (int kx=0; kx<3; ++kx){
      float w = src[ky*3+kx];
      sq += w*w;
      const int a = 2-ky, b = 2-kx;
      const int cy = (a==1)?0:1, cx = (b==1)?0:1;
      const int cls = cy*2 + cx;
      const int g   = (cls==3) ? ((a==0)?0:1) : 0;
      const int idx = (cls==1||cls==3) ? ((b==0)?0:1) : ((cls==2) ? ((a==0)?0:1) : 0);
      const int NT  = (cls==0)?1:2;
      Wup3[ clsBase[cls] + ((((g<<2)+og)<<4) + ci)*(NT<<12) + o7*(NT<<5) + (idx<<5) + ch ] = f2b(w);
    }
  wsq_up[(o<<9)+i] = sq;
}

// c_w [o512][i512][3][3] -> Wc3[ky][og][ci][o128][kx3][ch32] (tile 12288 elem contiguous)
__global__ __launch_bounds__(256) void prep_w_c(const float* __restrict__ c_w,
                                                u16* __restrict__ Wc3, float* __restrict__ wsq_c){
  const int t = blockIdx.x*256 + threadIdx.x;
  const int i = t & 511, o = t >> 9;
  const float* src = c_w + ((o<<9) + i)*9;
  const int og = o>>7, o7 = o&127, ci = i>>5, ch = i&31;
  float sq = 0.f;
  #pragma unroll
  for (int ky=0; ky<3; ++ky)
    #pragma unroll
    for (int kx=0; kx<3; ++kx){
      float w = src[ky*3+kx];
      sq += w*w;
      Wc3[ ((((ky<<2)+og)<<4) + ci)*12288 + o7*96 + (kx<<5) + ch ] = f2b(w);
    }
  wsq_c[(o<<9)+i] = sq;
}

__global__ __launch_bounds__(256) void prep_s(const float* __restrict__ v,
    const float* __restrict__ up_sw, const float* __restrict__ up_sb,
    const float* __restrict__ c_sw,  const float* __restrict__ c_sb,
    const float* __restrict__ rgb_sw,const float* __restrict__ rgb_sb,
    float* __restrict__ s_up, float* __restrict__ s_c, float* __restrict__ s_rgb){
  const int t = blockIdx.x*256 + threadIdx.x;          // 8*512
  const int j = t & 511, n = t >> 9;
  const float* vn = v + (n<<9);
  float a=0.f, b=0.f, c=0.f;
  for (int l=0; l<512; ++l){
    float vl = vn[l];
    a += vl*up_sw[(l<<9)+j];
    b += vl*c_sw[(l<<9)+j];
    c += vl*rgb_sw[(l<<9)+j];
  }
  s_up[t] = a + up_sb[j];
  s_c[t]  = b + c_sb[j];
  s_rgb[t]= c + rgb_sb[j];
}

__global__ __launch_bounds__(256) void prep_sigma(const float* __restrict__ wsq_up, const float* __restrict__ wsq_c,
    const float* __restrict__ s_up, const float* __restrict__ s_c,
    float* __restrict__ sinv_up, float* __restrict__ sinv_c){
  const int t = blockIdx.x*256 + threadIdx.x;          // 8*512
  const int o = t & 511, n = t >> 9;
  const float* su = s_up + (n<<9);
  const float* sc = s_c  + (n<<9);
  const float* wu = wsq_up + (o<<9);
  const float* wc = wsq_c  + (o<<9);
  float au=0.f, ac=0.f;
  for (int l=0; l<512; ++l){
    float s1 = su[l]; au += wu[l]*s1*s1;
    float s2 = sc[l]; ac += wc[l]*s2*s2;
  }
  sinv_up[t] = 1.f/sqrtf(au + 1e-8f);
  sinv_c[t]  = 1.f/sqrtf(ac + 1e-8f);
}

// zero only the padding ring of h1s [8][66][66][512]
__global__ __launch_bounds__(256) void zero_h1s_ring(u16* __restrict__ h1s){
  const int t = blockIdx.x*256 + threadIdx.x;   // 520*256
  const int chunk = t & 63;
  const int cg = t >> 6;                         // 0..2079
  const int n = cg / 260, c = cg - n*260;
  int Y, X;
  if (c < 66){ Y = 0; X = c; }
  else if (c < 132){ Y = 65; X = c - 66; }
  else if (c < 196){ Y = c - 131; X = 0; }
  else { Y = c - 195; X = 65; }
  u16x8 z = {0,0,0,0,0,0,0,0};
  *(u16x8*)&h1s[ (size_t)(((n*66 + Y)*66 + X)<<9) + (chunk<<3) ] = z;
}

// zero padding of xp [8][33][36][512]
__global__ __launch_bounds__(256) void zero_xp_ring(u16* __restrict__ xp){
  const int t = blockIdx.x*256 + threadIdx.x;   // 328*256
  const int chunk = t & 63;
  const int cg = t >> 6;                         // 0..1311
  const int n = cg / 164, c = cg - n*164;
  int p, q;
  if (c < 128){ p = c >> 2; q = 32 + (c & 3); }
  else { p = 32; q = c - 128; }
  u16x8 z = {0,0,0,0,0,0,0,0};
  *(u16x8*)&xp[ (size_t)(((n*33 + p)*36 + q)<<9) + (chunk<<3) ] = z;
}

// x [8,512,32,32] f32 -> xp NHWC bf16 [n][33][36][512], value = x * s_up[n][ch]
__global__ __launch_bounds__(256) void fill_xp(const float* __restrict__ x,
    const float* __restrict__ s_up, u16* __restrict__ xp){
  const int b = blockIdx.x;            // 256
  const int n = b>>5, p = b&31;
  const int t = threadIdx.x;
  const int q = t&31, g = t>>5;        // g 0..7
  const int cb = g<<6;
  #pragma unroll
  for (int j=0;j<8;++j){
    const int ch0 = cb + (j<<3);
    u16x8 pk;
    #pragma unroll
    for (int e=0;e<8;++e){
      float vv = x[ (((n<<9)+ch0+e)<<10) + (p<<5) + q ] * s_up[(n<<9)+ch0+e];
      pk[e] = f2b(vv);
    }
    *(u16x8*)&xp[ (((n*33+p)*36 + q)<<9) + ch0 ] = pk;
  }
}

// ---------------- up-conv (modulated conv_transpose 2x) ----------------
// long-phase pipeline: phase = (ci32ch, tap-group); A 2-buf LDS, patch [5][34][32] 2-buf LDS
// 1 barrier + vmcnt(0) per phase; loads issued at window start hide under MFMA
__global__ __launch_bounds__(256, 2) void up_conv_k(
    const u16* __restrict__ xp, const u16* __restrict__ Wup3,
    const float* __restrict__ sinv_up, const float* __restrict__ up_b,
    const float* __restrict__ s_c, const float* __restrict__ noise1,
    const float* __restrict__ nstr, u16* __restrict__ h1s)
{
  __shared__ __align__(16) u16 Ab[2][8192];    // [o128][idx(NT)][ch32]
  __shared__ __align__(16) u16 Pb[2][5632];    // [5][34][32]
  const int braw = blockIdx.x;
  const int bid = ((braw&7)<<7) | (braw>>3);   // XCD swizzle: n pinned per XCD
  const int og = bid & 3, tile = (bid>>2)&7, cls = (bid>>5)&3, n = bid>>7;
  const int cy = cls>>1, cx = cls&1;
  const int o0 = og<<7, r0 = tile<<2;
  const int tid = threadIdx.x;
  const int lane = tid & 63, w = tid>>6;
  const int l15 = lane & 15, l4 = lane>>4;
  const int wm = w>>1, wn = w&1;
  const int NT = (cls==0)?1:2;
  const int G  = (cls==3)?2:1;
  const int NPH = G<<4;
  const int clsBase[4] = {0, 262144, 786432, 1310720};
  const u16* Wb = Wup3 + clsBase[cls];
  const int tilesz = NT<<12;                   // 128*NT*32

  f32x4 acc[4][4];
  #pragma unroll
  for (int i2=0;i2<4;++i2)
    #pragma unroll
    for (int j2=0;j2<4;++j2){ f32x4 z = {0.f,0.f,0.f,0.f}; acc[i2][j2]=z; }

  auto issueA = [&](int p){
    const int ci = (G==2) ? (p>>1) : p;
    const int g  = (G==2) ? (p&1)  : 0;
    const u16* src0 = Wb + ((((g<<2)+og)<<4) + ci)*tilesz;
    u16* dst0 = Ab[p&1];
    const int nI = NT<<1;                      // 2 or 4 instrs per wave
    #pragma unroll
    for (int j=0;j<4;++j){
      if (j < nI){
        const int m = w*nI + j;
        gll16(src0 + (m<<9) + (lane<<3), dst0 + (m<<9));
      }
    }
  };
  auto issueP = [&](int ci){
    const int i0 = ci<<5;
    u16* dst0 = Pb[ci&1];
    #pragma unroll
    for (int j=0;j<3;++j){
      const int m = w + (j<<2);
      if (m < 11){
        int cell = (m<<4) + (lane>>2);
        cell = cell > 169 ? 169 : cell;
        const int row = cell/34, col = cell - row*34;
        const u16* src = xp + ((size_t)((n*33 + r0+row)*36 + col)<<9) + i0 + ((lane&3)<<3);
        gll16(src, dst0 + (m<<9));
      }
    }
  };
  auto compute = [&](int p){
    const int g  = (G==2) ? (p&1) : 0;
    const int ci = (G==2) ? (p>>1) : p;
    const u16* Abuf = Ab[p&1];
    const u16* Pbuf = Pb[ci&1];
    #pragma unroll
    for (int idx=0; idx<2; ++idx){
      if (idx < NT){
        const int dp = (cls==2) ? idx : ((cls==3) ? g : 0);
        const int dq = (cls==1 || cls==3) ? idx : 0;
        bf16x8 af[4], bq[4];
        #pragma unroll
        for (int fm=0;fm<4;++fm)
          af[fm] = *(const bf16x8*)&Abuf[ ((wm<<6)+(fm<<4)+l15)*(NT<<5) + (idx<<5) + (l4<<3) ];
        #pragma unroll
        for (int fn=0;fn<4;++fn){
          const int row = (wn<<1) + (fn>>1) + dp;
          const int col = ((fn&1)<<4) + l15 + dq;
          bq[fn] = *(const bf16x8*)&Pbuf[ ((row*34+col)<<5) + (l4<<3) ];
        }
        __builtin_amdgcn_s_setprio(1);
        #pragma unroll
        for (int fm=0;fm<4;++fm)
          #pragma unroll
          for (int fn=0;fn<4;++fn)
            acc[fm][fn] = __builtin_amdgcn_mfma_f32_16x16x32_bf16(af[fm], bq[fn], acc[fm][fn], 0,0,0);
        __builtin_amdgcn_s_setprio(0);
      }
    }
  };

  issueP(0); issueA(0);
  VMCNT0(); BAR();
  #pragma unroll 1
  for (int p=0; p<NPH; ++p){
    if (p+1 < NPH) issueA(p+1);
    {
      const int ci = (G==2) ? (p>>1) : p;
      const int g  = (G==2) ? (p&1)  : 0;
      if (g==0 && ci < 15) issueP(ci+1);
    }
    compute(p);
    VMCNT0();
    BAR();
  }

  // epilogue: demod + bias + noise + lrelu, fold s_c, store NHWC u16x4
  const float ns = nstr[0];
  #pragma unroll
  for (int fm=0; fm<4; ++fm){
    const int oo0 = o0 + (wm<<6) + (fm<<4) + (l4<<2);
    float si[4], bb[4], sc2[4];
    #pragma unroll
    for (int r=0;r<4;++r){
      si[r] = sinv_up[(n<<9)+oo0+r];
      bb[r] = up_b[oo0+r];
      sc2[r]= s_c[(n<<9)+oo0+r];
    }
    #pragma unroll
    for (int fn=0; fn<4; ++fn){
      const int rr = (wn<<1) + (fn>>1), c = ((fn&1)<<4) + l15;
      const int Y = ((r0+rr)<<1) + cy, X = (c<<1) + cx;
      const float nz = ns * noise1[(n<<12) + (Y<<6) + X];
      u16x4 pk;
      #pragma unroll
      for (int r=0;r<4;++r){
        float v2 = acc[fm][fn][r]*si[r] + bb[r] + nz;
        pk[r] = f2b(lrelu(v2) * sc2[r]);
      }
      *(u16x4*)&h1s[ (size_t)(((n*66 + Y+1)*66 + (X+1))<<9) + oo0 ] = pk;
    }
  }
}

// ---------------- 3x3 modulated conv ----------------
// 48 phases = 16 ci (32ch) x 3 ky; per phase 3 kx merged (A tile [128][96] = 24.6KB)
// A 2-buf, patch [6][34][32] 2-buf (staged at ky==0, 3 phases ahead); 1 bar + vmcnt0/phase
__global__ __launch_bounds__(256, 2) void conv3x3_k(
    const u16* __restrict__ h1s, const u16* __restrict__ Wc3,
    const float* __restrict__ sinv_c, const float* __restrict__ c_b,
    const float* __restrict__ noise2, const float* __restrict__ nstr,
    float* __restrict__ outh)
{
  __shared__ __align__(16) u16 Ab[2][12288];   // [o128][kx3][ch32]
  __shared__ __align__(16) u16 Pb[2][6656];    // [6][34][32]
  const int braw = blockIdx.x;
  const int bid = ((braw&7)<<7) | (braw>>3);   // XCD swizzle
  const int og = bid & 3, xt = (bid>>2)&1, yt = (bid>>3)&15, n = bid>>7;
  const int o0 = og<<7, y0 = yt<<2, x0 = xt<<5;
  const int tid = threadIdx.x;
  const int lane = tid & 63, w = tid>>6;
  const int l15 = lane & 15, l4 = lane>>4;
  const int wm = w>>1, wn = w&1;

  f32x4 acc[4][4];
  #pragma unroll
  for (int i2=0;i2<4;++i2)
    #pragma unroll
    for (int j2=0;j2<4;++j2){ f32x4 z = {0.f,0.f,0.f,0.f}; acc[i2][j2]=z; }

  auto issueA = [&](int p){
    const int ci = p/3, ky = p - ci*3;
    const u16* src0 = Wc3 + ((((ky<<2)+og)<<4) + ci)*12288;
    u16* dst0 = Ab[p&1];
    #pragma unroll
    for (int j=0;j<6;++j){
      const int m = w*6 + j;
      gll16(src0 + (m<<9) + (lane<<3), dst0 + (m<<9));
    }
  };
  auto issueP = [&](int ci){
    const int i0 = ci<<5;
    u16* dst0 = Pb[ci&1];
    #pragma unroll
    for (int j=0;j<4;++j){
      const int m = w + (j<<2);
      if (m < 13){
        int cell = (m<<4) + (lane>>2);
        cell = cell > 203 ? 203 : cell;
        const int row = cell/34, col = cell - row*34;
        const u16* src = h1s + ((size_t)((n*66 + y0+row)*66 + x0+col)<<9) + i0 + ((lane&3)<<3);
        gll16(src, dst0 + (m<<9));
      }
    }
  };
  auto compute = [&](int p){
    const int ci = p/3, ky = p - ci*3;
    const u16* Abuf = Ab[p&1];
    const u16* Pbuf = Pb[ci&1];
    #pragma unroll
    for (int kx=0;kx<3;++kx){
      bf16x8 af[4], bq[4];
      #pragma unroll
      for (int fm=0;fm<4;++fm)
        af[fm] = *(const bf16x8*)&Abuf[ ((wm<<6)+(fm<<4)+l15)*96 + (kx<<5) + (l4<<3) ];
      #pragma unroll
      for (int fn=0;fn<4;++fn){
        const int row = (wn<<1) + (fn>>1) + ky;
        const int col = ((fn&1)<<4) + l15 + kx;
        bq[fn] = *(const bf16x8*)&Pbuf[ ((row*34+col)<<5) + (l4<<3) ];
      }
      __builtin_amdgcn_s_setprio(1);
      #pragma unroll
      for (int fm=0;fm<4;++fm)
        #pragma unroll
        for (int fn=0;fn<4;++fn)
          acc[fm][fn] = __builtin_amdgcn_mfma_f32_16x16x32_bf16(af[fm], bq[fn], acc[fm][fn], 0,0,0);
      __builtin_amdgcn_s_setprio(0);
    }
  };

  issueP(0); issueA(0);
  VMCNT0(); BAR();
  #pragma unroll 1
  for (int p=0; p<48; ++p){
    if (p+1 < 48) issueA(p+1);
    {
      const int ci = p/3;
      if (p - ci*3 == 0 && ci < 15) issueP(ci+1);
    }
    compute(p);
    VMCNT0();
    BAR();
  }

  const float ns = nstr[0];
  #pragma unroll
  for (int fm=0; fm<4; ++fm){
    #pragma unroll
    for (int r=0;r<4;++r){
      const int oo = o0 + (wm<<6)+(fm<<4)+(l4<<2)+r;
      const float si = sinv_c[(n<<9)+oo], bb = c_b[oo];
      #pragma unroll
      for (int fn=0; fn<4; ++fn){
        const int Y = y0 + (wn<<1) + (fn>>1);
        const int X = x0 + ((fn&1)<<4) + l15;
        float v2 = acc[fm][fn][r]*si + bb + ns*noise2[(n<<12)+(Y<<6)+X];
        outh[ (size_t)(((n<<9)+oo)<<12) + (Y<<6) + X ] = lrelu(v2);
      }
    }
  }
}

// ---------------- toRGB + bilinear skip ----------------
__global__ __launch_bounds__(256) void rgb_k(const float* __restrict__ h2,
    const float* __restrict__ s_rgb, const float* __restrict__ rgb_w, const float* __restrict__ rgb_b,
    const float* __restrict__ yin, float* __restrict__ out1)
{
  __shared__ float coef[3][512];
  __shared__ float part[4][3][64];
  const int braw = blockIdx.x;
  const int sb = ((braw&7)<<6) | (braw>>3);    // XCD swizzle (512 blocks)
  const int n = sb>>6, Y = sb&63;
  const int tid = threadIdx.x;
  for (int t = tid; t < 1536; t += 256){
    int c = t>>9, o = t&511;
    coef[c][o] = rgb_w[(c<<9)+o]*s_rgb[(n<<9)+o];
  }
  __syncthreads();
  const int wave = tid>>6, lane = tid&63;
  const float* base = h2 + ((size_t)(n<<9))*4096 + (Y<<6) + lane;
  float a0=0.f,a1=0.f,a2=0.f;
  for (int e=0;e<128;++e){
    int o = (wave<<7)+e;
    float h = base[(size_t)o<<12];
    a0 += h*coef[0][o]; a1 += h*coef[1][o]; a2 += h*coef[2][o];
  }
  part[wave][0][lane]=a0; part[wave][1][lane]=a1; part[wave][2][lane]=a2;
  __syncthreads();
  if (tid < 192){
    const int c = tid>>6, x2 = tid&63;
    float s = part[0][c][x2]+part[1][c][x2]+part[2][c][x2]+part[3][c][x2] + rgb_b[c];
    s = lrelu(s);
    float fy = 0.5f*Y - 0.25f, fx = 0.5f*x2 - 0.25f;
    int y0i = (int)floorf(fy); float wy = fy - y0i;
    int x0i = (int)floorf(fx); float wx = fx - x0i;
    int y0c = y0i<0?0:y0i, y1c = y0i+1>31?31:y0i+1;
    int x0c = x0i<0?0:x0i, x1c = x0i+1>31?31:x0i+1;
    const float* yb = yin + ((n*3 + c)<<10);
    float v00 = yb[(y0c<<5)+x0c], v01 = yb[(y0c<<5)+x1c];
    float v10 = yb[(y1c<<5)+x0c], v11 = yb[(y1c<<5)+x1c];
    float yup = (1.f-wy)*((1.f-wx)*v00 + wx*v01) + wy*((1.f-wx)*v10 + wx*v11);
    out1[ (((n*3+c)<<12)) + (Y<<6) + x2 ] = yup + s;
  }
}

// ---------------- launch ----------------
extern "C" void kernel_launch(void* const* d_in, const int* in_sizes, int n_in,
                              void* d_out, int out_size, void* d_ws, size_t ws_size,
                              hipStream_t stream) {
  const float* x      = (const float*)d_in[0];
  const float* v      = (const float*)d_in[1];
  const float* yin    = (const float*)d_in[2];
  const float* noise1 = (const float*)d_in[3];
  const float* noise2 = (const float*)d_in[4];
  const float* up_w   = (const float*)d_in[5];
  const float* up_b   = (const float*)d_in[6];
  const float* up_sw  = (const float*)d_in[7];
  const float* up_sb  = (const float*)d_in[8];
  const float* c_w    = (const float*)d_in[9];
  const float* c_b    = (const float*)d_in[10];
  const float* c_sw   = (const float*)d_in[11];
  const float* c_sb   = (const float*)d_in[12];
  const float* rgb_w  = (const float*)d_in[13];
  const float* rgb_b  = (const float*)d_in[14];
  const float* rgb_sw = (const float*)d_in[15];
  const float* rgb_sb = (const float*)d_in[16];
  const float* nstr   = (const float*)d_in[17];

  char* w = (char*)d_ws;
  u16*   Wup3   = (u16*)(w);                  //  4,718,592 B
  u16*   Wc3    = (u16*)(w + 4718592);        //  4,718,592 B
  float* wsq_up = (float*)(w + 9437184);      //  1,048,576 B
  float* wsq_c  = (float*)(w + 10485760);     //  1,048,576 B
  float* s_up   = (float*)(w + 11534336);
  float* s_c    = (float*)(w + 11550720);
  float* s_rgb  = (float*)(w + 11567104);
  float* sinv_up= (float*)(w + 11583488);
  float* sinv_c = (float*)(w + 11599872);
  u16*   xp     = (u16*)(w + 11616256);       //  9,732,096 B  NHWC [8][33][36][512]
  u16*   h1s    = (u16*)(w + 21348352);       // 35,684,352 B  NHWC [8][66][66][512]

  float* outh = (float*)d_out;                 // [8,512,64,64]
  float* out1 = (float*)d_out + 16777216;      // [8,3,64,64]

  prep_w_up    <<<1024, 256, 0, stream>>>(up_w, Wup3, wsq_up);
  prep_w_c     <<<1024, 256, 0, stream>>>(c_w,  Wc3,  wsq_c);
  prep_s       <<<16,   256, 0, stream>>>(v, up_sw, up_sb, c_sw, c_sb, rgb_sw, rgb_sb, s_up, s_c, s_rgb);
  prep_sigma   <<<16,   256, 0, stream>>>(wsq_up, wsq_c, s_up, s_c, sinv_up, sinv_c);
  zero_xp_ring <<<328,  256, 0, stream>>>(xp);
  zero_h1s_ring<<<520,  256, 0, stream>>>(h1s);
  fill_xp      <<<256,  256, 0, stream>>>(x, s_up, xp);
  up_conv_k    <<<1024, 256, 0, stream>>>(xp, Wup3, sinv_up, up_b, s_c, noise1, nstr, h1s);
  conv3x3_k    <<<1024, 256, 0, stream>>>(h1s, Wc3, sinv_c, c_b, noise2, nstr, outh);
  rgb_k        <<<512,  256, 0, stream>>>(outh, s_rgb, rgb_w, rgb_b, yin, out1);
}